// Round 4
// baseline (658.723 us; speedup 1.0000x reference)
//
#include <hip/hip_runtime.h>
#include <math.h>

// Problem constants (fixed by the reference)
#define B_ROWS 4096
#define C_COLS 32768
#define BLOCK  1024
#define NF4    (C_COLS / 4 / BLOCK)   // 8 float4 per thread = full row in regs
#define GRID   256                    // 1 block per CU
#define RPB    (B_ROWS / GRID)        // 16 rows per block, software-pipelined

typedef float v4f __attribute__((ext_vector_type(4)));

// Light workgroup barrier: waits LDS ops only (lgkmcnt(0)); does NOT drain
// vmcnt, so prefetched global loads stay in flight across the barrier.
// s_waitcnt simm16 (gfx9/CDNA): vmcnt[3:0]+[15:14]=63, expcnt[6:4]=7,
// lgkmcnt[11:8]=0  ->  0xC07F.
__device__ __forceinline__ void bar_lds() {
    __builtin_amdgcn_s_waitcnt(0xC07F);
    __builtin_amdgcn_s_barrier();
}

__device__ __forceinline__ float wave_reduce_sum(float v) {
    #pragma unroll
    for (int off = 32; off > 0; off >>= 1)
        v += __shfl_down(v, off, 64);
    return v;
}

// Block-wide sum over 1024 threads (16 waves), LDS-only barriers.
__device__ __forceinline__ float block_reduce_sum(float v, float* red, int tid) {
    const int wid  = tid >> 6;
    const int lane = tid & 63;
    v = wave_reduce_sum(v);
    if (lane == 0) red[wid] = v;
    bar_lds();
    if (wid == 0) {
        float s = (lane < 16) ? red[lane] : 0.0f;
        #pragma unroll
        for (int off = 8; off > 0; off >>= 1)
            s += __shfl_down(s, off, 64);
        if (lane == 0) red[0] = s;
    }
    bar_lds();
    return red[0];
}

__global__ __launch_bounds__(BLOCK, 4)   // VGPR cap 128: 64 data regs + temps, no spill
void focal_row_kernel(const float* __restrict__ inp,
                      const int*   __restrict__ tgt,
                      float*       __restrict__ row_loss) {
    constexpr float SCALE = 30.0f;
    constexpr float COSM  = 0.9553364891f;   // cos(0.3)
    constexpr float SINM  = 0.2955202067f;   // sin(0.3)

    const int tid  = threadIdx.x;
    const int row0 = blockIdx.x * RPB;

    __shared__ float red_a[16];
    __shared__ float red_b[16];

    v4f buf[2][NF4];

    // Preload row 0 of this block's strip + its target element.
    {
        const v4f* __restrict__ p = (const v4f*)(inp + (size_t)row0 * C_COLS);
        #pragma unroll
        for (int k = 0; k < NF4; ++k)
            buf[0][k] = __builtin_nontemporal_load(p + (k * BLOCK + tid));
    }
    float xt = 0.0f;
    if (tid == 0) xt = inp[(size_t)row0 * C_COLS + tgt[row0]];

    #pragma unroll 2
    for (int i = 0; i < RPB; ++i) {
        const int row = row0 + i;
        v4f* cur = buf[i & 1];
        v4f* nxt = buf[(i + 1) & 1];

        // Consume current row: sum of squares (waits only cur's loads).
        float sumsq = 0.0f;
        #pragma unroll
        for (int k = 0; k < NF4; ++k) {
            sumsq = fmaf(cur[k].x, cur[k].x, sumsq);
            sumsq = fmaf(cur[k].y, cur[k].y, sumsq);
            sumsq = fmaf(cur[k].z, cur[k].z, sumsq);
            sumsq = fmaf(cur[k].w, cur[k].w, sumsq);
        }

        // Prefetch next row BEFORE the barriers; light barriers won't drain it.
        float xt_next = 0.0f;
        if (i + 1 < RPB) {
            const v4f* __restrict__ p = (const v4f*)(inp + (size_t)(row + 1) * C_COLS);
            #pragma unroll
            for (int k = 0; k < NF4; ++k)
                nxt[k] = __builtin_nontemporal_load(p + (k * BLOCK + tid));
            if (tid == 0) xt_next = inp[(size_t)(row + 1) * C_COLS + tgt[row + 1]];
        }

        const float total_sq = block_reduce_sum(sumsq, red_a, tid);
        const float norm = fmaxf(sqrtf(total_sq), 1e-12f);
        const float inv  = SCALE / norm;

        // |logit| <= 30 so fp32 exp is safe without max-subtraction.
        float se = 0.0f;
        #pragma unroll
        for (int k = 0; k < NF4; ++k) {
            se += __expf(cur[k].x * inv);
            se += __expf(cur[k].y * inv);
            se += __expf(cur[k].z * inv);
            se += __expf(cur[k].w * inv);
        }
        const float sumexp_full = block_reduce_sum(se, red_b, tid);

        if (tid == 0) {
            const float c  = xt / norm;                       // cos(theta)
            const float cc = fminf(fmaxf(c, -1.0f + 1e-7f), 1.0f - 1e-7f);
            const float sin_t = sqrtf(fmaxf(1.0f - cc * cc, 0.0f));
            const float cosm  = cc * COSM - sin_t * SINM;     // cos(theta + m)
            const float lt    = SCALE * cosm;                 // target logit

            const float Z  = sumexp_full - __expf(SCALE * c) + __expf(lt);
            const float ce = logf(Z) - lt;                    // -log_softmax[target]
            const float pt = __expf(-ce);
            const float om = 1.0f - pt;
            row_loss[row] = om * om * ce;                     // gamma = 2.0
        }
        xt = xt_next;
    }
}

// Single block: mean of 4096 per-row losses -> out[0].
__global__ __launch_bounds__(1024)
void finalize_kernel(const float* __restrict__ row_loss,
                     float*       __restrict__ out) {
    const int tid = threadIdx.x;
    __shared__ float red[16];
    float s = 0.0f;
    #pragma unroll
    for (int k = 0; k < B_ROWS / 1024; ++k)
        s += row_loss[k * 1024 + tid];
    const float total = block_reduce_sum(s, red, tid);
    if (tid == 0) out[0] = total * (1.0f / (float)B_ROWS);
}

extern "C" void kernel_launch(void* const* d_in, const int* in_sizes, int n_in,
                              void* d_out, int out_size, void* d_ws, size_t ws_size,
                              hipStream_t stream) {
    const float* inp = (const float*)d_in[0];
    const int*   tgt = (const int*)d_in[1];
    float*       out = (float*)d_out;
    float*       row_loss = (float*)d_ws;   // 4096 floats = 16 KB scratch

    focal_row_kernel<<<GRID, BLOCK, 0, stream>>>(inp, tgt, row_loss);
    finalize_kernel<<<1, 1024, 0, stream>>>(row_loss, out);
}